// Round 3
// baseline (416.993 us; speedup 1.0000x reference)
//
#include <hip/hip_runtime.h>

#define HW 16384
#define IGN 5
#define ROWS_TOTAL 12288
#define ANCH_ELEMS (ROWS_TOTAL * 256)

typedef __bf16 bf16x8 __attribute__((ext_vector_type(8)));
typedef float f32x4 __attribute__((ext_vector_type(4)));
typedef unsigned long long ull;

#define GLDS16(g, l)                                                                     \
    __builtin_amdgcn_global_load_lds((__attribute__((address_space(1))) const void*)(g), \
                                     (__attribute__((address_space(3))) void*)(l), 16, 0, 0)

// element offset into a 64-elem-per-row bf16 tile, XOR-swizzled at 16B granularity
__device__ __forceinline__ int swz_off(int row, int chunk) {
    return row * 64 + ((chunk ^ (row & 7)) * 8);
}

// class segment info from a row-tile base (tiles never straddle class segments:
// segments are 4096/2048-aligned, tiles are 64 rows)
__device__ __forceinline__ void cls_of(int mb, int& cc, int& r0, int& mv) {
    if (mb < 4096) { cc = 0; r0 = mb; mv = 4096; }
    else { cc = 1 + ((mb - 4096) >> 11); r0 = (mb - 4096) & 2047; mv = 2048; }
}

// ---------------- fused prep launch ----------------------------------------------
// blocks [0,64):    argmax(labels[0, ::8, ::8]) + per-chunk class masks
// blocks [64,512):  weight f32->bf16 convert (w1,w2,w3), float4-vectorized
// blocks [512,2560): feats[0] transpose + f32->bf16, 64x64 tiles, bf16x8 stores
__global__ void prep_fused(const float* __restrict__ labels, const int* __restrict__ predicts,
                           ull* __restrict__ maskH, ull* __restrict__ maskE,
                           const float* __restrict__ w1, const float* __restrict__ w2,
                           const float* __restrict__ w3, __bf16* __restrict__ w1b,
                           __bf16* __restrict__ w2b, __bf16* __restrict__ w3b,
                           const float* __restrict__ F, __bf16* __restrict__ Xb) {
    __shared__ float t[64][68];  // pad 68: float4-aligned rows, banks spread by 4
    int bid = blockIdx.x;
    int tid = threadIdx.x;
    if (bid < 64) {
        // ---- prep: argmax + masks
        int p = bid * 256 + tid;
        int pr = p >> 7, pc = p & 127;
        const float* lp = labels + ((size_t)(pr * 8) * 1024 + (size_t)(pc * 8)) * 5;
        float best = lp[0];
        int bi = 0;
#pragma unroll
        for (int c = 1; c < 5; ++c) {
            float v = lp[c];
            if (v > best) { best = v; bi = c; }
        }
        int yy = predicts[p];
        int chunk = p >> 6;
        int lane = tid & 63;
#pragma unroll
        for (int c = 0; c < 5; ++c) {
            ull mh = __ballot(bi == c && yy != c);
            ull me = __ballot(bi == c && yy == c);
            if (lane == 0) {
                maskH[c * 256 + chunk] = mh;
                maskE[c * 256 + chunk] = me;
            }
        }
    } else if (bid < 512) {
        // ---- weight convert: 448 blocks * 256 thr * 4 elems = 458752 exactly
        int base = ((bid - 64) * 256 + tid) * 4;
        if (base < 262144) {
            float4 v = *(const float4*)(w1 + base);
            w1b[base + 0] = (__bf16)v.x; w1b[base + 1] = (__bf16)v.y;
            w1b[base + 2] = (__bf16)v.z; w1b[base + 3] = (__bf16)v.w;
        } else if (base < 393216) {
            int o = base - 262144;
            float4 v = *(const float4*)(w2 + o);
            w2b[o + 0] = (__bf16)v.x; w2b[o + 1] = (__bf16)v.y;
            w2b[o + 2] = (__bf16)v.z; w2b[o + 3] = (__bf16)v.w;
        } else {
            int o = base - 393216;
            float4 v = *(const float4*)(w3 + o);
            w3b[o + 0] = (__bf16)v.x; w3b[o + 1] = (__bf16)v.y;
            w3b[o + 2] = (__bf16)v.z; w3b[o + 3] = (__bf16)v.w;
        }
    } else {
        // ---- conv_x: 64 pix x 64 ch tile; float4 loads, bf16x8 stores
        int cid = bid - 512;             // 0..2047
        int pb = (cid & 255) * 64;       // pixel tile
        int chb = (cid >> 8) * 64;       // channel tile
        int row = tid >> 2;              // channel within tile (0..63)
        int seg = tid & 3;               // 16-float segment
        const float* src = F + (size_t)(chb + row) * HW + pb + seg * 16;
#pragma unroll
        for (int k = 0; k < 4; ++k)
            *(float4*)&t[row][seg * 16 + k * 4] = *(const float4*)(src + k * 4);
        __syncthreads();
        int p = tid >> 2;                // pixel within tile (0..63)
        __bf16* dst = Xb + (size_t)(pb + p) * 512 + chb + seg * 16;
        bf16x8 o0, o1;
#pragma unroll
        for (int j = 0; j < 8; ++j) o0[j] = (__bf16)t[seg * 16 + j][p];
#pragma unroll
        for (int j = 0; j < 8; ++j) o1[j] = (__bf16)t[seg * 16 + 8 + j][p];
        *(bf16x8*)dst = o0;
        *(bf16x8*)(dst + 8) = o1;
    }
}

// ---------------- GEMM1: H1 = leaky(Xb[fwd] * W1^T + b1), 64x256 tile, BK=64 -----
// fwd derived IN-BLOCK from the class masks (wave 0) while kt=0 B loads fly.
// 4 waves 2x2, each 32 rows x 128 cols.
__global__ __launch_bounds__(256) void gemm1_bt(const __bf16* __restrict__ A,
                                                const ull* __restrict__ maskH,
                                                const ull* __restrict__ maskE,
                                                const __bf16* __restrict__ Bw,
                                                const float* __restrict__ bias,
                                                __bf16* __restrict__ C) {
    const int K = 512, N = 512, BK = 64;
    __shared__ __bf16 As[64 * 64];    // 8 KB
    __shared__ __bf16 Bs[256 * 64];   // 32 KB
    __shared__ int fwd_s[64];
    int tid = threadIdx.x;
    int lane = tid & 63;
    int wave_base = tid & 0xC0;  // wave*64, uniform per wave
    int wave = tid >> 6;
    int wm = (wave >> 1) * 32, wn = (wave & 1) * 128;
    int mb = blockIdx.x * 64, nb = blockIdx.y * 256;
    int l15 = lane & 15, quad = lane >> 4;

    // B staging sources (independent of fwd) + pre-issue kt=0 B tile
    const __bf16* srcB[8];
#pragma unroll
    for (int r = 0; r < 8; ++r) {
        int cc2 = tid + r * 256;          // 0..2047
        int row = cc2 >> 3, ch = cc2 & 7; // row 0..255
        srcB[r] = Bw + (size_t)(nb + row) * K + ((ch ^ (row & 7)) * 8);
    }
#pragma unroll
    for (int r = 0; r < 8; ++r)
        GLDS16(srcB[r], Bs + (size_t)(r * 256 + wave_base) * 8);

    // wave 0: derive this tile's 64 fwd entries from the masks
    if (wave == 0) {
        int cc, r0, mv;
        cls_of(mb, cc, r0, mv);
        const ull* MH = maskH + cc * 256;
        const ull* ME = maskE + cc * 256;
        ull mh[4], me[4];
        int ph[4], pe[4];
        int sh = 0, se = 0;
#pragma unroll
        for (int k = 0; k < 4; ++k) {
            int ch = lane * 4 + k;
            mh[k] = MH[ch];
            me[k] = ME[ch];
            ph[k] = sh; sh += __popcll(mh[k]);
            pe[k] = se; se += __popcll(me[k]);
        }
        int incH = sh, incE = se;
#pragma unroll
        for (int d = 1; d < 64; d <<= 1) {
            int tt = __shfl_up(incH, d);
            if (lane >= d) incH += tt;
            tt = __shfl_up(incE, d);
            if (lane >= d) incE += tt;
        }
        int exH = incH - sh, exE = incE - se;
        int nh = __shfl(incH, 63), ne = __shfl(incE, 63);
        int cnt = nh + ne;
        int n_sel = (cnt > 1) ? ((cnt < mv) ? cnt : mv) : 0;
        int hk;
        if ((2 * nh >= n_sel) && (2 * ne >= n_sel)) hk = n_sel >> 1;
        else if (2 * nh >= n_sel) hk = n_sel - ne;
        else hk = nh;
        int ek = n_sel - hk;
        fwd_s[lane] = -1;  // in-wave LDS ordering: init issues before expansion writes
        // hard: ranks [r0, r0+64) ∩ [0, hk)
        int lo = r0, hi = min(r0 + 64, hk);
#pragma unroll
        for (int k = 0; k < 4; ++k) {
            int base = exH + ph[k];
            ull mm = mh[k];
            if (base < hi && base + __popcll(mm) > lo) {
                int j = 0;
                while (mm) {
                    int b = __ffsll(mm) - 1;
                    mm &= mm - 1;
                    int rk = base + j; ++j;
                    if (rk >= lo && rk < hi) fwd_s[rk - r0] = (lane * 4 + k) * 64 + b;
                }
            }
        }
        // easy: row-rank hk+e; e in [max(0,r0-hk), min(r0+64-hk, ek))
        int elo = r0 - hk;
        if (elo < 0) elo = 0;
        int ehi = min(r0 + 64 - hk, ek);
#pragma unroll
        for (int k = 0; k < 4; ++k) {
            int base = exE + pe[k];
            ull mm = me[k];
            if (base < ehi && base + __popcll(mm) > elo) {
                int j = 0;
                while (mm) {
                    int b = __ffsll(mm) - 1;
                    mm &= mm - 1;
                    int rk = base + j; ++j;
                    if (rk >= elo && rk < ehi) fwd_s[hk + rk - r0] = (lane * 4 + k) * 64 + b;
                }
            }
        }
    }
    __syncthreads();  // fwd_s ready; kt=0 B tile drained (vmcnt) by barrier semantics

    // A staging sources via in-LDS fwd
    const __bf16* srcA[2];
#pragma unroll
    for (int r = 0; r < 2; ++r) {
        int cc2 = tid + r * 256;          // 0..511
        int row = cc2 >> 3, ch = cc2 & 7; // row 0..63
        int pix = fwd_s[row];
        if (pix < 0) pix = 0;
        srcA[r] = A + (size_t)pix * K + ((ch ^ (row & 7)) * 8);
    }

    f32x4 acc[2][8] = {};

    for (int kt = 0; kt < K; kt += BK) {
#pragma unroll
        for (int r = 0; r < 2; ++r)
            GLDS16(srcA[r] + kt, As + (size_t)(r * 256 + wave_base) * 8);
        if (kt) {
#pragma unroll
            for (int r = 0; r < 8; ++r)
                GLDS16(srcB[r] + kt, Bs + (size_t)(r * 256 + wave_base) * 8);
        }
        __syncthreads();
#pragma unroll
        for (int kk = 0; kk < 2; ++kk) {  // two 32-wide K-steps
            bf16x8 af[2], bq[8];
#pragma unroll
            for (int i = 0; i < 2; ++i)
                af[i] = *(const bf16x8*)(As + swz_off(wm + i * 16 + l15, quad + kk * 4));
#pragma unroll
            for (int j = 0; j < 8; ++j)
                bq[j] = *(const bf16x8*)(Bs + swz_off(wn + j * 16 + l15, quad + kk * 4));
#pragma unroll
            for (int i = 0; i < 2; ++i)
#pragma unroll
                for (int j = 0; j < 8; ++j)
                    acc[i][j] = __builtin_amdgcn_mfma_f32_16x16x32_bf16(af[i], bq[j], acc[i][j], 0, 0, 0);
        }
        __syncthreads();
    }

#pragma unroll
    for (int i = 0; i < 2; ++i) {
#pragma unroll
        for (int j = 0; j < 8; ++j) {
            int col = nb + wn + j * 16 + l15;
            float bv = bias[col];
#pragma unroll
            for (int r = 0; r < 4; ++r) {
                int row = mb + wm + i * 16 + quad * 4 + r;
                float v = acc[i][j][r] + bv;
                v = (v >= 0.f) ? v : 0.2f * v;
                C[(size_t)row * N + col] = (__bf16)v;
            }
        }
    }
}

// ---------------- fused GEMM2+GEMM3 + row-norm + y_ labels -----------------------
// block = 64 rows x 256 cols, 4 waves 2x2 (each 32 rows x 128 cols). Phase A:
// H2 = leaky(H1@W2^T+b2) kept in LDS. Phase B: H3 = H2s@W3^T+b3 -> norm ->
// masked f32 write. W2/W3 staged once per 64 rows (was per 32).
__global__ __launch_bounds__(256) void gemm23_norm(const __bf16* __restrict__ H1,
                                                   const __bf16* __restrict__ W2b,
                                                   const float* __restrict__ b2,
                                                   const __bf16* __restrict__ W3b,
                                                   const float* __restrict__ b3,
                                                   const ull* __restrict__ maskH,
                                                   const ull* __restrict__ maskE,
                                                   float* __restrict__ out) {
    __shared__ __bf16 As[64 * 64];       // 8 KB
    __shared__ __bf16 Ws[256 * 64];      // 32 KB (shared by phase A and B)
    __shared__ __bf16 H2s[4][64 * 64];   // 32 KB: 4 K-blocks, swizzled like As
    __shared__ float nrm[64];
    int tid = threadIdx.x;
    int lane = tid & 63, wave = tid >> 6;
    int wave_base = tid & 0xC0;
    int l15 = lane & 15, quad = lane >> 4;
    int mb = blockIdx.x * 64;
    int wm = (wave >> 1) * 32, wn = (wave & 1) * 128;
    int cc, r0, mv;
    cls_of(mb, cc, r0, mv);

    // staging sources (XOR-pre-swizzled global addresses, linear LDS dest)
    const __bf16* srcA[2];
#pragma unroll
    for (int r = 0; r < 2; ++r) {
        int cc2 = tid + r * 256;          // 0..511
        int row = cc2 >> 3, ch = cc2 & 7; // row 0..63
        srcA[r] = H1 + (size_t)(mb + row) * 512 + ((ch ^ (row & 7)) * 8);
    }
    const __bf16* srcW2[8];
#pragma unroll
    for (int r = 0; r < 8; ++r) {
        int cc2 = tid + r * 256;
        int row = cc2 >> 3, ch = cc2 & 7;  // row 0..255
        srcW2[r] = W2b + (size_t)row * 512 + ((ch ^ (row & 7)) * 8);
    }
    // pre-issue kt=0 loads, then compute n_sel under their latency
#pragma unroll
    for (int r = 0; r < 2; ++r)
        GLDS16(srcA[r], As + (size_t)(r * 256 + wave_base) * 8);
#pragma unroll
    for (int r = 0; r < 8; ++r)
        GLDS16(srcW2[r], Ws + (size_t)(r * 256 + wave_base) * 8);

    int n_sel = 0;  // valid in wave 0 only (sole consumer: tid<64 epilogue)
    if (wave == 0) {
        int sh = 0, se = 0;
#pragma unroll
        for (int k = 0; k < 4; ++k) {
            sh += __popcll(maskH[cc * 256 + lane * 4 + k]);
            se += __popcll(maskE[cc * 256 + lane * 4 + k]);
        }
#pragma unroll
        for (int d = 1; d < 64; d <<= 1) {
            sh += __shfl_xor(sh, d);
            se += __shfl_xor(se, d);
        }
        int cnt = sh + se;
        n_sel = (cnt > 1) ? ((cnt < mv) ? cnt : mv) : 0;
    }
    if (tid < 64) nrm[tid] = 0.f;

    // ---- phase A: H2 = leaky(H1 @ W2^T + b2), M=64 N=256 K=512
    f32x4 acc[2][8] = {};
    for (int kt = 0; kt < 512; kt += 64) {
        if (kt) {
#pragma unroll
            for (int r = 0; r < 2; ++r)
                GLDS16(srcA[r] + kt, As + (size_t)(r * 256 + wave_base) * 8);
#pragma unroll
            for (int r = 0; r < 8; ++r)
                GLDS16(srcW2[r] + kt, Ws + (size_t)(r * 256 + wave_base) * 8);
        }
        __syncthreads();
#pragma unroll
        for (int kk = 0; kk < 2; ++kk) {
            bf16x8 af[2], bq[8];
#pragma unroll
            for (int i = 0; i < 2; ++i)
                af[i] = *(const bf16x8*)(As + swz_off(wm + i * 16 + l15, quad + kk * 4));
#pragma unroll
            for (int j = 0; j < 8; ++j)
                bq[j] = *(const bf16x8*)(Ws + swz_off(wn + j * 16 + l15, quad + kk * 4));
#pragma unroll
            for (int i = 0; i < 2; ++i)
#pragma unroll
                for (int j = 0; j < 8; ++j)
                    acc[i][j] = __builtin_amdgcn_mfma_f32_16x16x32_bf16(af[i], bq[j], acc[i][j], 0, 0, 0);
        }
        __syncthreads();
    }

    // phase-B W3 tile 0: issue now, hide under epilogue A (Ws free after last sync)
    const __bf16* srcW3[8];
#pragma unroll
    for (int r = 0; r < 8; ++r) {
        int cc2 = tid + r * 256;
        int row = cc2 >> 3, ch = cc2 & 7;
        srcW3[r] = W3b + (size_t)row * 256 + ((ch ^ (row & 7)) * 8);
    }
#pragma unroll
    for (int r = 0; r < 8; ++r)
        GLDS16(srcW3[r], Ws + (size_t)(r * 256 + wave_base) * 8);

    // epilogue A: bias+leaky, store into H2s with the same swizzle ds_read expects
#pragma unroll
    for (int i = 0; i < 2; ++i) {
#pragma unroll
        for (int j = 0; j < 8; ++j) {
            int col = wn + j * 16 + l15;       // H2 k-index 0..255
            float bv = b2[col];
            int ktb = col >> 6;
            int chunk = (col >> 3) & 7;
#pragma unroll
            for (int r = 0; r < 4; ++r) {
                int row = wm + i * 16 + quad * 4 + r;  // 0..63
                float v = acc[i][j][r] + bv;
                v = (v >= 0.f) ? v : 0.2f * v;
                H2s[ktb][row * 64 + ((chunk ^ (row & 7)) * 8) + (col & 7)] = (__bf16)v;
            }
        }
    }
    __syncthreads();

    // ---- phase B: H3 = H2s @ W3^T + b3, M=64 N=256 K=256
    f32x4 acc3[2][8] = {};
    for (int ktb = 0; ktb < 4; ++ktb) {
        if (ktb) {
#pragma unroll
            for (int r = 0; r < 8; ++r)
                GLDS16(srcW3[r] + ktb * 64, Ws + (size_t)(r * 256 + wave_base) * 8);
            __syncthreads();
        }
#pragma unroll
        for (int kk = 0; kk < 2; ++kk) {
            bf16x8 af[2], bq[8];
#pragma unroll
            for (int i = 0; i < 2; ++i)
                af[i] = *(const bf16x8*)(&H2s[ktb][0] + swz_off(wm + i * 16 + l15, quad + kk * 4));
#pragma unroll
            for (int j = 0; j < 8; ++j)
                bq[j] = *(const bf16x8*)(Ws + swz_off(wn + j * 16 + l15, quad + kk * 4));
#pragma unroll
            for (int i = 0; i < 2; ++i)
#pragma unroll
                for (int j = 0; j < 8; ++j)
                    acc3[i][j] = __builtin_amdgcn_mfma_f32_16x16x32_bf16(af[i], bq[j], acc3[i][j], 0, 0, 0);
        }
        __syncthreads();
    }

    // epilogue B: bias, per-row sum-of-squares (shfl within 16-lane col groups),
    // masked 1/norm factor, y_ labels, scaled f32 write
    float bvs[8];
#pragma unroll
    for (int j = 0; j < 8; ++j) bvs[j] = b3[wn + j * 16 + l15];
    float ss[2][4];
#pragma unroll
    for (int i = 0; i < 2; ++i)
#pragma unroll
        for (int r = 0; r < 4; ++r) ss[i][r] = 0.f;
#pragma unroll
    for (int i = 0; i < 2; ++i)
#pragma unroll
        for (int j = 0; j < 8; ++j)
#pragma unroll
            for (int r = 0; r < 4; ++r) {
                float v = acc3[i][j][r] + bvs[j];
                ss[i][r] += v * v;
            }
#pragma unroll
    for (int i = 0; i < 2; ++i) {
#pragma unroll
        for (int r = 0; r < 4; ++r) {
            float s = ss[i][r];
            s += __shfl_xor(s, 1);
            s += __shfl_xor(s, 2);
            s += __shfl_xor(s, 4);
            s += __shfl_xor(s, 8);
            if (l15 == 0) atomicAdd(&nrm[wm + i * 16 + quad * 4 + r], s);
        }
    }
    __syncthreads();
    if (tid < 64) {  // tid<64 is wave 0: n_sel is live here
        float f = 1.0f / fmaxf(sqrtf(nrm[tid]), 1e-12f);
        int ok = (r0 + tid) < n_sel;
        nrm[tid] = ok ? f : 0.f;  // invalid rows -> exact 0 output
        out[ANCH_ELEMS + mb + tid] = (float)(ok ? cc : IGN);
    }
    __syncthreads();
#pragma unroll
    for (int i = 0; i < 2; ++i) {
#pragma unroll
        for (int j = 0; j < 8; ++j) {
            int col = wn + j * 16 + l15;
#pragma unroll
            for (int r = 0; r < 4; ++r) {
                int row = wm + i * 16 + quad * 4 + r;
                out[(size_t)(mb + row) * 256 + col] = (acc3[i][j][r] + bvs[j]) * nrm[row];
            }
        }
    }
}

extern "C" void kernel_launch(void* const* d_in, const int* in_sizes, int n_in,
                              void* d_out, int out_size, void* d_ws, size_t ws_size,
                              hipStream_t stream) {
    const float* feats = (const float*)d_in[0];
    const float* labels = (const float*)d_in[1];
    const int* predicts = (const int*)d_in[2];
    const float* w1 = (const float*)d_in[3];
    const float* b1 = (const float*)d_in[4];
    const float* w2 = (const float*)d_in[5];
    const float* b2 = (const float*)d_in[6];
    const float* w3 = (const float*)d_in[7];
    const float* b3 = (const float*)d_in[8];
    float* out = (float*)d_out;
    char* ws = (char*)d_ws;

    ull* maskH = (ull*)(ws + (136 << 10));  // 10 KB
    ull* maskE = (ull*)(ws + (148 << 10));  // 10 KB
    __bf16* w1b = (__bf16*)(ws + (256 << 10));
    __bf16* w2b = (__bf16*)(ws + (768 << 10));
    __bf16* w3b = (__bf16*)(ws + (1024 << 10));
    __bf16* Xb = (__bf16*)(ws + (2ull << 20));   // 16384x512 bf16 = 16MB
    __bf16* H1 = (__bf16*)(ws + (18ull << 20));  // 12288x512 bf16 = 12MB

    // 1: masks (64) + weight convert (448) + feats transpose/convert (2048)
    prep_fused<<<2560, 256, 0, stream>>>(labels, predicts, maskH, maskE,
                                         w1, w2, w3, w1b, w2b, w3b, feats, Xb);
    // 2: H1 = leaky(Xb[fwd] @ W1^T + b1); fwd derived in-block from masks
    gemm1_bt<<<dim3(192, 2), 256, 0, stream>>>(Xb, maskH, maskE, w1b, b1, H1);
    // 3: H3 = (leaky(H1 @ W2^T + b2)) @ W3^T + b3 -> row-norm -> masked write + y_
    gemm23_norm<<<192, 256, 0, stream>>>(H1, w2b, b2, w3b, b3, maskH, maskE, out);
}

// Round 4
// 408.990 us; speedup vs baseline: 1.0196x; 1.0196x over previous
//
#include <hip/hip_runtime.h>

#define HW 16384
#define IGN 5
#define ROWS_TOTAL 12288
#define ANCH_ELEMS (ROWS_TOTAL * 256)

typedef __bf16 bf16x8 __attribute__((ext_vector_type(8)));
typedef float f32x4 __attribute__((ext_vector_type(4)));
typedef unsigned long long ull;

#define GLDS16(g, l)                                                                     \
    __builtin_amdgcn_global_load_lds((__attribute__((address_space(1))) const void*)(g), \
                                     (__attribute__((address_space(3))) void*)(l), 16, 0, 0)

// element offset into a 64-elem-per-row bf16 tile, XOR-swizzled at 16B granularity
__device__ __forceinline__ int swz_off(int row, int chunk) {
    return row * 64 + ((chunk ^ (row & 7)) * 8);
}

// class segment info from a row-tile base (tiles never straddle class segments:
// segments are 4096/2048-aligned, tiles are 32/64 rows)
__device__ __forceinline__ void cls_of(int mb, int& cc, int& r0, int& mv) {
    if (mb < 4096) { cc = 0; r0 = mb; mv = 4096; }
    else { cc = 1 + ((mb - 4096) >> 11); r0 = (mb - 4096) & 2047; mv = 2048; }
}

// ---------------- fused prep launch ----------------------------------------------
// blocks [0,64):    argmax(labels[0, ::8, ::8]) + per-chunk class masks
// blocks [64,512):  weight f32->bf16 convert (w1,w2,w3), float4-vectorized
// blocks [512,2560): feats[0] transpose + f32->bf16, 64x64 tiles, bf16x8 stores
__global__ void prep_fused(const float* __restrict__ labels, const int* __restrict__ predicts,
                           ull* __restrict__ maskH, ull* __restrict__ maskE,
                           const float* __restrict__ w1, const float* __restrict__ w2,
                           const float* __restrict__ w3, __bf16* __restrict__ w1b,
                           __bf16* __restrict__ w2b, __bf16* __restrict__ w3b,
                           const float* __restrict__ F, __bf16* __restrict__ Xb) {
    __shared__ float t[64][68];  // pad 68: float4-aligned rows, banks spread by 4
    int bid = blockIdx.x;
    int tid = threadIdx.x;
    if (bid < 64) {
        // ---- prep: argmax + masks (no global y_hat/fwd needed anymore)
        int p = bid * 256 + tid;
        int pr = p >> 7, pc = p & 127;
        const float* lp = labels + ((size_t)(pr * 8) * 1024 + (size_t)(pc * 8)) * 5;
        float best = lp[0];
        int bi = 0;
#pragma unroll
        for (int c = 1; c < 5; ++c) {
            float v = lp[c];
            if (v > best) { best = v; bi = c; }
        }
        int yy = predicts[p];
        int chunk = p >> 6;
        int lane = tid & 63;
#pragma unroll
        for (int c = 0; c < 5; ++c) {
            ull mh = __ballot(bi == c && yy != c);
            ull me = __ballot(bi == c && yy == c);
            if (lane == 0) {
                maskH[c * 256 + chunk] = mh;
                maskE[c * 256 + chunk] = me;
            }
        }
    } else if (bid < 512) {
        // ---- weight convert: 448 blocks * 256 thr * 4 elems = 458752 exactly
        int base = ((bid - 64) * 256 + tid) * 4;
        if (base < 262144) {
            float4 v = *(const float4*)(w1 + base);
            w1b[base + 0] = (__bf16)v.x; w1b[base + 1] = (__bf16)v.y;
            w1b[base + 2] = (__bf16)v.z; w1b[base + 3] = (__bf16)v.w;
        } else if (base < 393216) {
            int o = base - 262144;
            float4 v = *(const float4*)(w2 + o);
            w2b[o + 0] = (__bf16)v.x; w2b[o + 1] = (__bf16)v.y;
            w2b[o + 2] = (__bf16)v.z; w2b[o + 3] = (__bf16)v.w;
        } else {
            int o = base - 393216;
            float4 v = *(const float4*)(w3 + o);
            w3b[o + 0] = (__bf16)v.x; w3b[o + 1] = (__bf16)v.y;
            w3b[o + 2] = (__bf16)v.z; w3b[o + 3] = (__bf16)v.w;
        }
    } else {
        // ---- conv_x: 64 pix x 64 ch tile; float4 loads, bf16x8 stores
        int cid = bid - 512;             // 0..2047
        int pb = (cid & 255) * 64;       // pixel tile
        int chb = (cid >> 8) * 64;       // channel tile
        int row = tid >> 2;              // channel within tile (0..63)
        int seg = tid & 3;               // 16-float segment
        const float* src = F + (size_t)(chb + row) * HW + pb + seg * 16;
#pragma unroll
        for (int k = 0; k < 4; ++k)
            *(float4*)&t[row][seg * 16 + k * 4] = *(const float4*)(src + k * 4);
        __syncthreads();
        int p = tid >> 2;                // pixel within tile (0..63)
        __bf16* dst = Xb + (size_t)(pb + p) * 512 + chb + seg * 16;
        bf16x8 o0, o1;
#pragma unroll
        for (int j = 0; j < 8; ++j) o0[j] = (__bf16)t[seg * 16 + j][p];
#pragma unroll
        for (int j = 0; j < 8; ++j) o1[j] = (__bf16)t[seg * 16 + 8 + j][p];
        *(bf16x8*)dst = o0;
        *(bf16x8*)(dst + 8) = o1;
    }
}

// ---------------- GEMM1: H1 = leaky(Xb[fwd] * W1^T + b1), 64x128 tile, BK=64 -----
// fwd is derived IN-BLOCK from the class masks (wave 0: prefix scan of the 256
// chunk popcounts + bit-expansion of the <=3 chunks covering this tile's 64 ranks)
// while the other waves' kt=0 B-tile loads are already in flight.
__global__ __launch_bounds__(256) void gemm1_bt(const __bf16* __restrict__ A,
                                                const ull* __restrict__ maskH,
                                                const ull* __restrict__ maskE,
                                                const __bf16* __restrict__ Bw,
                                                const float* __restrict__ bias,
                                                __bf16* __restrict__ C) {
    const int K = 512, N = 512, BK = 64;
    __shared__ __bf16 As[64 * 64];
    __shared__ __bf16 Bs[128 * 64];
    __shared__ int fwd_s[64];
    int tid = threadIdx.x;
    int lane = tid & 63;
    int wave_base = tid & 0xC0;  // wave*64, uniform per wave
    int wave = tid >> 6;
    int wm = (wave >> 1) * 32, wn = (wave & 1) * 64;
    int mb = blockIdx.x * 64, nb = blockIdx.y * 128;
    int l15 = lane & 15, quad = lane >> 4;

    // B staging sources (independent of fwd) + pre-issue kt=0 B tile
    const __bf16* srcB[4];
#pragma unroll
    for (int r = 0; r < 4; ++r) {
        int cc2 = tid + r * 256;          // 0..1023
        int row = cc2 >> 3, ch = cc2 & 7; // row 0..127
        srcB[r] = Bw + (size_t)(nb + row) * K + ((ch ^ (row & 7)) * 8);
    }
#pragma unroll
    for (int r = 0; r < 4; ++r)
        GLDS16(srcB[r], Bs + (size_t)(r * 256 + wave_base) * 8);

    // wave 0: derive this tile's 64 fwd entries from the masks
    if (wave == 0) {
        int cc, r0, mv;
        cls_of(mb, cc, r0, mv);
        const ull* MH = maskH + cc * 256;
        const ull* ME = maskE + cc * 256;
        ull mh[4], me[4];
        int ph[4], pe[4];
        int sh = 0, se = 0;
#pragma unroll
        for (int k = 0; k < 4; ++k) {
            int ch = lane * 4 + k;
            mh[k] = MH[ch];
            me[k] = ME[ch];
            ph[k] = sh; sh += __popcll(mh[k]);
            pe[k] = se; se += __popcll(me[k]);
        }
        int incH = sh, incE = se;
#pragma unroll
        for (int d = 1; d < 64; d <<= 1) {
            int tt = __shfl_up(incH, d);
            if (lane >= d) incH += tt;
            tt = __shfl_up(incE, d);
            if (lane >= d) incE += tt;
        }
        int exH = incH - sh, exE = incE - se;
        int nh = __shfl(incH, 63), ne = __shfl(incE, 63);
        int cnt = nh + ne;
        int n_sel = (cnt > 1) ? ((cnt < mv) ? cnt : mv) : 0;
        int hk;
        if ((2 * nh >= n_sel) && (2 * ne >= n_sel)) hk = n_sel >> 1;
        else if (2 * nh >= n_sel) hk = n_sel - ne;
        else hk = nh;
        int ek = n_sel - hk;
        fwd_s[lane] = -1;  // in-wave LDS ordering: init issues before expansion writes
        // hard: ranks [r0, r0+64) ∩ [0, hk)
        int lo = r0, hi = min(r0 + 64, hk);
#pragma unroll
        for (int k = 0; k < 4; ++k) {
            int base = exH + ph[k];
            ull mm = mh[k];
            if (base < hi && base + __popcll(mm) > lo) {
                int j = 0;
                while (mm) {
                    int b = __ffsll(mm) - 1;
                    mm &= mm - 1;
                    int rk = base + j; ++j;
                    if (rk >= lo && rk < hi) fwd_s[rk - r0] = (lane * 4 + k) * 64 + b;
                }
            }
        }
        // easy: row-rank hk+e; e in [max(0,r0-hk), min(r0+64-hk, ek))
        int elo = r0 - hk;
        if (elo < 0) elo = 0;
        int ehi = min(r0 + 64 - hk, ek);
#pragma unroll
        for (int k = 0; k < 4; ++k) {
            int base = exE + pe[k];
            ull mm = me[k];
            if (base < ehi && base + __popcll(mm) > elo) {
                int j = 0;
                while (mm) {
                    int b = __ffsll(mm) - 1;
                    mm &= mm - 1;
                    int rk = base + j; ++j;
                    if (rk >= elo && rk < ehi) fwd_s[hk + rk - r0] = (lane * 4 + k) * 64 + b;
                }
            }
        }
    }
    __syncthreads();  // fwd_s ready; kt=0 B tile drained (vmcnt) by barrier semantics

    // A staging sources via in-LDS fwd
    const __bf16* srcA[2];
#pragma unroll
    for (int r = 0; r < 2; ++r) {
        int cc2 = tid + r * 256;          // 0..511
        int row = cc2 >> 3, ch = cc2 & 7; // row 0..63
        int pix = fwd_s[row];
        if (pix < 0) pix = 0;
        srcA[r] = A + (size_t)pix * K + ((ch ^ (row & 7)) * 8);
    }

    f32x4 acc[2][4] = {};

    for (int kt = 0; kt < K; kt += BK) {
#pragma unroll
        for (int r = 0; r < 2; ++r)
            GLDS16(srcA[r] + kt, As + (size_t)(r * 256 + wave_base) * 8);
        if (kt) {
#pragma unroll
            for (int r = 0; r < 4; ++r)
                GLDS16(srcB[r] + kt, Bs + (size_t)(r * 256 + wave_base) * 8);
        }
        __syncthreads();
#pragma unroll
        for (int kk = 0; kk < 2; ++kk) {  // two 32-wide K-steps
            bf16x8 af[2], bq[4];
#pragma unroll
            for (int i = 0; i < 2; ++i)
                af[i] = *(const bf16x8*)(As + swz_off(wm + i * 16 + l15, quad + kk * 4));
#pragma unroll
            for (int j = 0; j < 4; ++j)
                bq[j] = *(const bf16x8*)(Bs + swz_off(wn + j * 16 + l15, quad + kk * 4));
#pragma unroll
            for (int i = 0; i < 2; ++i)
#pragma unroll
                for (int j = 0; j < 4; ++j)
                    acc[i][j] = __builtin_amdgcn_mfma_f32_16x16x32_bf16(af[i], bq[j], acc[i][j], 0, 0, 0);
        }
        __syncthreads();
    }

#pragma unroll
    for (int i = 0; i < 2; ++i) {
#pragma unroll
        for (int j = 0; j < 4; ++j) {
            int col = nb + wn + j * 16 + l15;
            float bv = bias[col];
#pragma unroll
            for (int r = 0; r < 4; ++r) {
                int row = mb + wm + i * 16 + quad * 4 + r;
                float v = acc[i][j][r] + bv;
                v = (v >= 0.f) ? v : 0.2f * v;
                C[(size_t)row * N + col] = (__bf16)v;
            }
        }
    }
}

// ---------------- fused GEMM2+GEMM3 + row-norm + y_ labels -----------------------
// block = 32 rows x 256 cols, 4 waves (each 32x64). Phase A: H2 = leaky(H1@W2^T+b2)
// kept in LDS. Phase B: H3 = H2s@W3^T+b3 -> norm -> masked f32 write. Validity and
// y_ labels derived from n_sel (wave-0 popcount of this block's class masks).
__global__ __launch_bounds__(256) void gemm23_norm(const __bf16* __restrict__ H1,
                                                   const __bf16* __restrict__ W2b,
                                                   const float* __restrict__ b2,
                                                   const __bf16* __restrict__ W3b,
                                                   const float* __restrict__ b3,
                                                   const ull* __restrict__ maskH,
                                                   const ull* __restrict__ maskE,
                                                   float* __restrict__ out) {
    __shared__ __bf16 As[32 * 64];       // 4 KB
    __shared__ __bf16 Ws[256 * 64];      // 32 KB (shared by phase A and B)
    __shared__ __bf16 H2s[4][32 * 64];   // 16 KB: 4 K-blocks, swizzled like As
    __shared__ float nrm[32];
    int tid = threadIdx.x;
    int lane = tid & 63, wave = tid >> 6;
    int wave_base = tid & 0xC0;
    int l15 = lane & 15, quad = lane >> 4;
    int mb = blockIdx.x * 32;
    int wn = wave * 64;  // this wave's 64 output cols
    int cc, r0, mv;
    cls_of(mb, cc, r0, mv);

    // staging sources (XOR-pre-swizzled global addresses, linear LDS dest)
    int rowA = tid >> 3, chA = tid & 7;  // A tile: 32 rows x 64 k = 1 round
    const __bf16* srcA = H1 + (size_t)(mb + rowA) * 512 + ((chA ^ (rowA & 7)) * 8);
    const __bf16* srcW2[8];
#pragma unroll
    for (int r = 0; r < 8; ++r) {
        int cc2 = tid + r * 256;
        int row = cc2 >> 3, ch = cc2 & 7;  // row 0..255
        srcW2[r] = W2b + (size_t)row * 512 + ((ch ^ (row & 7)) * 8);
    }
    // pre-issue kt=0 loads, then compute n_sel under their latency
    GLDS16(srcA, As + (size_t)wave_base * 8);
#pragma unroll
    for (int r = 0; r < 8; ++r)
        GLDS16(srcW2[r], Ws + (size_t)(r * 256 + wave_base) * 8);

    int n_sel = 0;  // valid in wave 0 only (sole consumer: tid<32 epilogue)
    if (wave == 0) {
        int sh = 0, se = 0;
#pragma unroll
        for (int k = 0; k < 4; ++k) {
            sh += __popcll(maskH[cc * 256 + lane * 4 + k]);
            se += __popcll(maskE[cc * 256 + lane * 4 + k]);
        }
#pragma unroll
        for (int d = 1; d < 64; d <<= 1) {
            sh += __shfl_xor(sh, d);
            se += __shfl_xor(se, d);
        }
        int cnt = sh + se;
        n_sel = (cnt > 1) ? ((cnt < mv) ? cnt : mv) : 0;
    }
    if (tid < 32) nrm[tid] = 0.f;

    // ---- phase A: H2 = leaky(H1 @ W2^T + b2), M=32 N=256 K=512
    f32x4 acc[2][4] = {};
    for (int kt = 0; kt < 512; kt += 64) {
        if (kt) {
            GLDS16(srcA + kt, As + (size_t)wave_base * 8);
#pragma unroll
            for (int r = 0; r < 8; ++r)
                GLDS16(srcW2[r] + kt, Ws + (size_t)(r * 256 + wave_base) * 8);
        }
        __syncthreads();
#pragma unroll
        for (int kk = 0; kk < 2; ++kk) {
            bf16x8 af[2], bq[4];
#pragma unroll
            for (int i = 0; i < 2; ++i)
                af[i] = *(const bf16x8*)(As + swz_off(i * 16 + l15, quad + kk * 4));
#pragma unroll
            for (int j = 0; j < 4; ++j)
                bq[j] = *(const bf16x8*)(Ws + swz_off(wn + j * 16 + l15, quad + kk * 4));
#pragma unroll
            for (int i = 0; i < 2; ++i)
#pragma unroll
                for (int j = 0; j < 4; ++j)
                    acc[i][j] = __builtin_amdgcn_mfma_f32_16x16x32_bf16(af[i], bq[j], acc[i][j], 0, 0, 0);
        }
        __syncthreads();
    }

    // phase-B W3 tile 0: issue now, hide under epilogue A (Ws is free after last sync)
    const __bf16* srcW3[8];
#pragma unroll
    for (int r = 0; r < 8; ++r) {
        int cc2 = tid + r * 256;
        int row = cc2 >> 3, ch = cc2 & 7;
        srcW3[r] = W3b + (size_t)row * 256 + ((ch ^ (row & 7)) * 8);
    }
#pragma unroll
    for (int r = 0; r < 8; ++r)
        GLDS16(srcW3[r], Ws + (size_t)(r * 256 + wave_base) * 8);

    // epilogue A: bias+leaky, store into H2s with the same swizzle ds_read expects
#pragma unroll
    for (int i = 0; i < 2; ++i) {
#pragma unroll
        for (int j = 0; j < 4; ++j) {
            int col = wn + j * 16 + l15;       // H2 k-index 0..255
            float bv = b2[col];
            int ktb = col >> 6;
            int chunk = (col >> 3) & 7;
#pragma unroll
            for (int r = 0; r < 4; ++r) {
                int row = i * 16 + quad * 4 + r;
                float v = acc[i][j][r] + bv;
                v = (v >= 0.f) ? v : 0.2f * v;
                H2s[ktb][row * 64 + ((chunk ^ (row & 7)) * 8) + (col & 7)] = (__bf16)v;
            }
        }
    }
    __syncthreads();

    // ---- phase B: H3 = H2s @ W3^T + b3, M=32 N=256 K=256
    f32x4 acc3[2][4] = {};
    for (int ktb = 0; ktb < 4; ++ktb) {
        if (ktb) {
#pragma unroll
            for (int r = 0; r < 8; ++r)
                GLDS16(srcW3[r] + ktb * 64, Ws + (size_t)(r * 256 + wave_base) * 8);
            __syncthreads();
        }
#pragma unroll
        for (int kk = 0; kk < 2; ++kk) {
            bf16x8 af[2], bq[4];
#pragma unroll
            for (int i = 0; i < 2; ++i)
                af[i] = *(const bf16x8*)(&H2s[ktb][0] + swz_off(i * 16 + l15, quad + kk * 4));
#pragma unroll
            for (int j = 0; j < 4; ++j)
                bq[j] = *(const bf16x8*)(Ws + swz_off(wn + j * 16 + l15, quad + kk * 4));
#pragma unroll
            for (int i = 0; i < 2; ++i)
#pragma unroll
                for (int j = 0; j < 4; ++j)
                    acc3[i][j] = __builtin_amdgcn_mfma_f32_16x16x32_bf16(af[i], bq[j], acc3[i][j], 0, 0, 0);
        }
        __syncthreads();
    }

    // epilogue B: bias, per-row sum-of-squares (shfl within 16-lane col groups),
    // masked 1/norm factor, y_ labels, scaled f32 write
    float vs[2][4][4];
    float ss[2][4];
#pragma unroll
    for (int i = 0; i < 2; ++i)
#pragma unroll
        for (int r = 0; r < 4; ++r) ss[i][r] = 0.f;
#pragma unroll
    for (int i = 0; i < 2; ++i) {
#pragma unroll
        for (int j = 0; j < 4; ++j) {
            int col = wn + j * 16 + l15;
            float bv = b3[col];
#pragma unroll
            for (int r = 0; r < 4; ++r) {
                float v = acc3[i][j][r] + bv;
                vs[i][j][r] = v;
                ss[i][r] += v * v;
            }
        }
    }
#pragma unroll
    for (int i = 0; i < 2; ++i) {
#pragma unroll
        for (int r = 0; r < 4; ++r) {
            float s = ss[i][r];
            s += __shfl_xor(s, 1);
            s += __shfl_xor(s, 2);
            s += __shfl_xor(s, 4);
            s += __shfl_xor(s, 8);
            if (l15 == 0) atomicAdd(&nrm[i * 16 + quad * 4 + r], s);
        }
    }
    __syncthreads();
    if (tid < 32) {  // tid<32 is wave 0: n_sel is live here
        float f = 1.0f / fmaxf(sqrtf(nrm[tid]), 1e-12f);
        int ok = (r0 + tid) < n_sel;
        nrm[tid] = ok ? f : 0.f;  // invalid rows -> exact 0 output
        out[ANCH_ELEMS + mb + tid] = (float)(ok ? cc : IGN);
    }
    __syncthreads();
#pragma unroll
    for (int i = 0; i < 2; ++i) {
#pragma unroll
        for (int j = 0; j < 4; ++j) {
            int col = wn + j * 16 + l15;
#pragma unroll
            for (int r = 0; r < 4; ++r) {
                int row = i * 16 + quad * 4 + r;
                out[(size_t)(mb + row) * 256 + col] = vs[i][j][r] * nrm[row];
            }
        }
    }
}

extern "C" void kernel_launch(void* const* d_in, const int* in_sizes, int n_in,
                              void* d_out, int out_size, void* d_ws, size_t ws_size,
                              hipStream_t stream) {
    const float* feats = (const float*)d_in[0];
    const float* labels = (const float*)d_in[1];
    const int* predicts = (const int*)d_in[2];
    const float* w1 = (const float*)d_in[3];
    const float* b1 = (const float*)d_in[4];
    const float* w2 = (const float*)d_in[5];
    const float* b2 = (const float*)d_in[6];
    const float* w3 = (const float*)d_in[7];
    const float* b3 = (const float*)d_in[8];
    float* out = (float*)d_out;
    char* ws = (char*)d_ws;

    ull* maskH = (ull*)(ws + (136 << 10));  // 10 KB
    ull* maskE = (ull*)(ws + (148 << 10));  // 10 KB
    __bf16* w1b = (__bf16*)(ws + (256 << 10));
    __bf16* w2b = (__bf16*)(ws + (768 << 10));
    __bf16* w3b = (__bf16*)(ws + (1024 << 10));
    __bf16* Xb = (__bf16*)(ws + (2ull << 20));   // 16384x512 bf16 = 16MB
    __bf16* H1 = (__bf16*)(ws + (18ull << 20));  // 12288x512 bf16 = 12MB

    // 1: masks (64) + weight convert (448) + feats transpose/convert (2048)
    prep_fused<<<2560, 256, 0, stream>>>(labels, predicts, maskH, maskE,
                                         w1, w2, w3, w1b, w2b, w3b, feats, Xb);
    // 2: H1 = leaky(Xb[fwd] @ W1^T + b1); fwd derived in-block from masks
    gemm1_bt<<<dim3(192, 4), 256, 0, stream>>>(Xb, maskH, maskE, w1b, b1, H1);
    // 3: H3 = (leaky(H1 @ W2^T + b2)) @ W3^T + b3 -> row-norm -> masked write + y_
    gemm23_norm<<<384, 256, 0, stream>>>(H1, w2b, b2, w3b, b3, maskH, maskE, out);
}